// Round 1
// baseline (363.237 us; speedup 1.0000x reference)
//
#include <hip/hip_runtime.h>
#include <hip/hip_bf16.h>

typedef __bf16 bf16_t;
typedef __bf16 bf16x8 __attribute__((ext_vector_type(8)));
typedef __bf16 bf16x2_t __attribute__((ext_vector_type(2)));
typedef float f32x4 __attribute__((ext_vector_type(4)));
typedef int   i32x4 __attribute__((ext_vector_type(4)));

#define MFMA16(A, B, C) __builtin_amdgcn_mfma_f32_16x16x32_bf16(A, B, C, 0, 0, 0)

// load 8 consecutive f32 (32B, 16B-aligned) and round to bf16x8 (RNE)
__device__ __forceinline__ bf16x8 load_cvt8(const float* __restrict__ p) {
    f32x4 a = *(const f32x4*)p;
    f32x4 b = *(const f32x4*)(p + 4);
    bf16x8 r;
    r[0] = (bf16_t)a[0]; r[1] = (bf16_t)a[1]; r[2] = (bf16_t)a[2]; r[3] = (bf16_t)a[3];
    r[4] = (bf16_t)b[0]; r[5] = (bf16_t)b[1]; r[6] = (bf16_t)b[2]; r[7] = (bf16_t)b[3];
    return r;
}

__device__ __forceinline__ int pack_bf16(float lo, float hi) {
    bf16x2_t t; t[0] = (bf16_t)lo; t[1] = (bf16_t)hi;
    return __builtin_bit_cast(int, t);
}

// H=8, B=256, L=128, D=64. One block per (h,b). 4 waves; wave w owns Q rows [32w,32w+32).
// QK^T computed TRANSPOSED (S^T = mfma(K,Q)): lane (g,c) owns q-row 16qt+c,
// k = 16kt+4g+r -> softmax needs only shfl_xor 16/32; bias loads + attn stores are f32x4.
// PV computed as out^T = mfma(V^T, P^T): out stores are f32x4. P reaches PV via ds_bpermute.
// LDS holds only Vt (17.4 KB) -> 3 blocks/CU with __launch_bounds__(256,3).
__global__ __launch_bounds__(256, 3)
void sdpa_kernel(const float* __restrict__ q, const float* __restrict__ kmat,
                 const float* __restrict__ v, const float* __restrict__ bias,
                 float* __restrict__ out, float* __restrict__ attn)
{
    constexpr int L = 128, D = 64;
    constexpr int VS = 136;  // Vt LDS stride (XOR-granule swizzled rows)
    __shared__ __align__(16) bf16_t Vt[D * VS];   // 17408 B total LDS

    const int bh   = blockIdx.x;        // h*256 + b
    const int h    = bh >> 8;
    const int tid  = threadIdx.x;
    const int w    = tid >> 6;          // wave 0..3
    const int lane = tid & 63;
    const int g    = lane >> 4;         // quad 0..3
    const int c    = lane & 15;

    const float* qb = q    + (size_t)bh * (L * D);
    const float* kb = kmat + (size_t)bh * (L * D);
    const float* vb = v    + (size_t)bh * (L * D);
    const float* bb = bias + (size_t)h  * (L * L);
    float* outb  = out  + (size_t)bh * (L * D);
    float* attnb = attn + (size_t)bh * (L * L);

    // ---- V -> registers (coalesced 32B/lane) -> swizzled Vt. Done first so vreg dies early.
    // Vt element (d,k) at d*VS + ((k>>3) ^ ((d>>3)&7))*8 + (k&7)
    {
        f32x4 vreg[4][2];
#pragma unroll
        for (int it = 0; it < 4; ++it) {
            const float* p = vb + tid * 8 + it * 2048;
            vreg[it][0] = *(const f32x4*)p;
            vreg[it][1] = *(const f32x4*)(p + 4);
        }
        const int pp = tid & 7, sl = tid >> 3;   // d-octet, k-row
#pragma unroll
        for (int it = 0; it < 4; ++it) {
            const int base = (((sl >> 3) + 4 * it) ^ pp) * 8 + (sl & 7);
#pragma unroll
            for (int j = 0; j < 8; ++j)
                Vt[(8 * pp + j) * VS + base] = (bf16_t)vreg[it][j >> 2][j & 3];
        }
    }

    // ---- Q fragments (MFMA B-operand): B[d=32kk+8g+j][n=c] = Q[32w+16qt+c][d]
    bf16x8 qf[2][2];
#pragma unroll
    for (int qt = 0; qt < 2; ++qt)
#pragma unroll
        for (int kk = 0; kk < 2; ++kk)
            qf[qt][kk] = load_cvt8(qb + (32 * w + 16 * qt + c) * D + kk * 32 + g * 8);

    // ---- S^T = K Q^T : 8 k-tiles x 2 q-tiles of 16x16, K(=d)=64 in 2 steps
    // acc[kt][qt][r] = S[q=32w+16qt+c][k=16kt+4g+r]
    f32x4 acc[8][2];
#pragma unroll
    for (int kt = 0; kt < 8; ++kt) {
        acc[kt][0] = f32x4{0.f, 0.f, 0.f, 0.f};
        acc[kt][1] = f32x4{0.f, 0.f, 0.f, 0.f};
    }
#pragma unroll
    for (int kt = 0; kt < 8; ++kt) {
        // A[m=c][d=8g+j(+32)] = K[16kt+c][d] : 32B contiguous per half
        bf16x8 kf0 = load_cvt8(kb + (16 * kt + c) * D + g * 8);
        bf16x8 kf1 = load_cvt8(kb + (16 * kt + c) * D + 32 + g * 8);
        acc[kt][0] = MFMA16(kf0, qf[0][0], acc[kt][0]);
        acc[kt][0] = MFMA16(kf1, qf[0][1], acc[kt][0]);
        acc[kt][1] = MFMA16(kf0, qf[1][0], acc[kt][1]);
        acc[kt][1] = MFMA16(kf1, qf[1][1], acc[kt][1]);
    }

    // ---- softmax (row q = 32w+16qt+c lives in the 4 lanes sharing c) + attn store + pack
    int pk[8][2][2];   // pk[kt][qt][h] = bf16x2( P[q][16kt+4g+2h], P[q][16kt+4g+2h+1] )
#pragma unroll
    for (int qt = 0; qt < 2; ++qt) {
        const int qrow = 32 * w + 16 * qt + c;
        const float* brow = bb + qrow * L;
        float* arow = attnb + qrow * L;

        float mkt[8];
#pragma unroll
        for (int kt = 0; kt < 8; ++kt) {
            const f32x4 bv = *(const f32x4*)(brow + 16 * kt + 4 * g);
            float s0 = acc[kt][qt][0] * 0.125f + bv[0];
            float s1 = acc[kt][qt][1] * 0.125f + bv[1];
            float s2 = acc[kt][qt][2] * 0.125f + bv[2];
            float s3 = acc[kt][qt][3] * 0.125f + bv[3];
            acc[kt][qt][0] = s0; acc[kt][qt][1] = s1;
            acc[kt][qt][2] = s2; acc[kt][qt][3] = s3;
            mkt[kt] = fmaxf(fmaxf(s0, s1), fmaxf(s2, s3));
        }
        float m = fmaxf(fmaxf(fmaxf(mkt[0], mkt[1]), fmaxf(mkt[2], mkt[3])),
                        fmaxf(fmaxf(mkt[4], mkt[5]), fmaxf(mkt[6], mkt[7])));
        m = fmaxf(m, __shfl_xor(m, 16));
        m = fmaxf(m, __shfl_xor(m, 32));

        float skt[8];
#pragma unroll
        for (int kt = 0; kt < 8; ++kt) {
            float e0 = exp2f((acc[kt][qt][0] - m) * 1.4426950408889634f);
            float e1 = exp2f((acc[kt][qt][1] - m) * 1.4426950408889634f);
            float e2 = exp2f((acc[kt][qt][2] - m) * 1.4426950408889634f);
            float e3 = exp2f((acc[kt][qt][3] - m) * 1.4426950408889634f);
            acc[kt][qt][0] = e0; acc[kt][qt][1] = e1;
            acc[kt][qt][2] = e2; acc[kt][qt][3] = e3;
            skt[kt] = (e0 + e1) + (e2 + e3);
        }
        float sum = ((skt[0] + skt[1]) + (skt[2] + skt[3])) +
                    ((skt[4] + skt[5]) + (skt[6] + skt[7]));
        sum += __shfl_xor(sum, 16);
        sum += __shfl_xor(sum, 32);
        const float inv = 1.0f / sum;

#pragma unroll
        for (int kt = 0; kt < 8; ++kt) {
            f32x4 o;
            o[0] = acc[kt][qt][0] * inv; o[1] = acc[kt][qt][1] * inv;
            o[2] = acc[kt][qt][2] * inv; o[3] = acc[kt][qt][3] * inv;
            *(f32x4*)(arow + 16 * kt + 4 * g) = o;       // attn: f32x4 straight from regs
            pk[kt][qt][0] = pack_bf16(o[0], o[1]);
            pk[kt][qt][1] = pack_bf16(o[2], o[3]);
        }
    }

    __syncthreads();   // Vt writes (top of kernel) -> Vt reads (below)

    // ---- out^T = V^T P^T : A = Vt rows (d=16dt+c), B = P fragments via ds_bpermute.
    // Fragment for (qt,kk): bf16[j] = P[16qt+c][32kk+8g+j]; source lanes c+32(g&1)(+16),
    // kt parity = g>>1 (lane>=32) selects odd-kt bpermute result.
    const int srcA = (c + 32 * (g & 1)) * 4;
    const int srcB = srcA + 64;
    const bool hi  = lane >= 32;

    f32x4 oacc[4][2];
#pragma unroll
    for (int dt = 0; dt < 4; ++dt) {
        oacc[dt][0] = f32x4{0.f, 0.f, 0.f, 0.f};
        oacc[dt][1] = f32x4{0.f, 0.f, 0.f, 0.f};
    }

#pragma unroll
    for (int kk = 0; kk < 4; ++kk) {
        bf16x8 pfrag[2];
#pragma unroll
        for (int qt = 0; qt < 2; ++qt) {
            const int e0 = __builtin_amdgcn_ds_bpermute(srcA, pk[2 * kk][qt][0]);
            const int o0 = __builtin_amdgcn_ds_bpermute(srcA, pk[2 * kk + 1][qt][0]);
            const int e1 = __builtin_amdgcn_ds_bpermute(srcA, pk[2 * kk][qt][1]);
            const int o1 = __builtin_amdgcn_ds_bpermute(srcA, pk[2 * kk + 1][qt][1]);
            const int e2 = __builtin_amdgcn_ds_bpermute(srcB, pk[2 * kk][qt][0]);
            const int o2 = __builtin_amdgcn_ds_bpermute(srcB, pk[2 * kk + 1][qt][0]);
            const int e3 = __builtin_amdgcn_ds_bpermute(srcB, pk[2 * kk][qt][1]);
            const int o3 = __builtin_amdgcn_ds_bpermute(srcB, pk[2 * kk + 1][qt][1]);
            i32x4 wv;
            wv[0] = hi ? o0 : e0;
            wv[1] = hi ? o1 : e1;
            wv[2] = hi ? o2 : e2;
            wv[3] = hi ? o3 : e3;
            pfrag[qt] = __builtin_bit_cast(bf16x8, wv);
        }
#pragma unroll
        for (int dt = 0; dt < 4; ++dt) {
            const int vr = 16 * dt + c;
            const bf16x8 vf =
                *(const bf16x8*)(&Vt[vr * VS + (((4 * kk + g) ^ ((vr >> 3) & 7)) * 8)]);
            oacc[dt][0] = MFMA16(vf, pfrag[0], oacc[dt][0]);
            oacc[dt][1] = MFMA16(vf, pfrag[1], oacc[dt][1]);
        }
    }

    // ---- out stores: out[q=32w+16qt+c][d=16dt+4g..+3] as f32x4 (16B, 16 rows x 64B/instr)
#pragma unroll
    for (int dt = 0; dt < 4; ++dt)
#pragma unroll
        for (int qt = 0; qt < 2; ++qt)
            *(f32x4*)(outb + (32 * w + 16 * qt + c) * D + 16 * dt + 4 * g) = oacc[dt][qt];
}

extern "C" void kernel_launch(void* const* d_in, const int* in_sizes, int n_in,
                              void* d_out, int out_size, void* d_ws, size_t ws_size,
                              hipStream_t stream) {
    const float* q  = (const float*)d_in[0];
    const float* k  = (const float*)d_in[1];
    const float* v  = (const float*)d_in[2];
    const float* pb = (const float*)d_in[3];
    float* out  = (float*)d_out;
    float* attn = out + (size_t)8 * 256 * 128 * 64;   // outputs concatenated: out then attn
    sdpa_kernel<<<dim3(8 * 256), dim3(256), 0, stream>>>(q, k, v, pb, out, attn);
}